// Round 13
// baseline (123.599 us; speedup 1.0000x reference)
//
#include <hip/hip_runtime.h>
#include <stdint.h>
#include <math.h>

#define NM 2048

typedef _Float16 f16;
typedef unsigned char u8;
typedef __attribute__((ext_vector_type(4))) float float4v;

// float -> OCP e4m3 byte (RNE, hardware convert; gfx950 = OCP format)
__device__ inline u8 to_fp8(float v) {
    return (u8)(__builtin_amdgcn_cvt_pk_fp8_f32(v, v, 0, false) & 0xff);
}

// ---------------------------------------------------------------------------
// X = A - A^T: f16 master plane + fp8 operand plane Xq = fp8(32*X).
// ---------------------------------------------------------------------------
__global__ void skew_f16_kernel(const float* __restrict__ A, f16* __restrict__ X,
                                u8* __restrict__ Xq) {
    __shared__ float t[32][33];
    const int bx = blockIdx.x * 32, by = blockIdx.y * 32;
    const int tx = threadIdx.x, ty = threadIdx.y;
    #pragma unroll
    for (int r = 0; r < 32; r += 8)
        t[ty + r][tx] = A[(size_t)(bx + ty + r) * NM + by + tx];
    __syncthreads();
    #pragma unroll
    for (int r = 0; r < 32; r += 8) {
        const int i = by + ty + r, j = bx + tx;
        const float x = A[(size_t)i * NM + j] - t[tx][ty + r];
        X[(size_t)i * NM + j]  = (f16)x;
        Xq[(size_t)i * NM + j] = to_fp8(32.0f * x);
    }
}

// ---------------------------------------------------------------------------
// Round-13: ALGEBRAIC halving of GEMM1.  r12 measured the occupancy ladder
// to exhaustion (1->2 blocks/CU -4us, 2->4 -2.6us; core stuck ~45us/GEMM).
// New lever: X skew => X2 = -X*X^T is EXACTLY symmetric, so GEMM1 only
// computes the lower triangle + diagonal (528 of 1024 tiles, 51.6%) and the
// epilogue mirrors each element: X2(j,i) = X2(i,j);
// CT(j,i) = 256*(X2(i,j)/24 + X(i,j)/6)   (X sign-flips under transpose).
// Diagonal-tile double-writes are bitwise-identical (A=B=Xq: acc(i,j) and
// acc(j,i) sum identical products in identical hardware order) -> benign.
// GEMM2 = r12's kernel unchanged (X2*C has no free symmetry).
//
// Core (r12-proven): 64x64 tiles, 4 waves (wave tile 32x32), BK=128 fp8,
// 16 K-tiles, 1-phase loop {stage T+1 -> other buf; read T; 16 MFMA; LG0;
// W0; BARRIER}; static 32KB LDS; launch_bounds(256,4).
// Hazards: STAGE@T -> other buf (last reads certified by T-1's LG0+BARRIER);
// RD@T reads cur buf staged at T-1 (certified by T-1's W0+BARRIER).
// ---------------------------------------------------------------------------
#define BARRIER asm volatile("s_barrier" ::: "memory")
#define LG0     asm volatile("s_waitcnt lgkmcnt(0)" ::: "memory")
#define W0      asm volatile("s_waitcnt vmcnt(0)" ::: "memory")
#define NOST    ((void)0)

#define GLL(src, dstoff)                                                      \
    __builtin_amdgcn_global_load_lds(                                         \
        (const __attribute__((address_space(1))) void*)(src),                 \
        (__attribute__((address_space(3))) void*)(uintptr_t)(dstoff),         \
        16, 0, 0)

#define STAGE(dst)                                                            \
    do {                                                                      \
        GLL(gA,                (dst) + loffA);                                \
        GLL(gA + 32 * NM,      (dst) + loffA + 4096);                         \
        GLL(gB,                (dst) + loffB);                                \
        GLL(gB + 32 * NM,      (dst) + loffB + 4096);                         \
        gA += 128; gB += 128;                                                 \
    } while (0)

#define RD_ALL(BB)                                                           \
    { _Pragma("unroll")                                                      \
      for (int r_ = 0; r_ < 2; ++r_)                                         \
        _Pragma("unroll")                                                    \
        for (int k_ = 0; k_ < 4; ++k_)                                       \
            ah[r_][k_] = *(const long*)((BB) + offA[r_][k_]);                \
      _Pragma("unroll")                                                      \
      for (int c_ = 0; c_ < 2; ++c_)                                         \
        _Pragma("unroll")                                                    \
        for (int k_ = 0; k_ < 4; ++k_)                                       \
            bh[c_][k_] = *(const long*)((BB) + offB[c_][k_]); }

#define MFMA16                                                               \
    __builtin_amdgcn_s_setprio(1);                                           \
    _Pragma("unroll")                                                        \
    for (int r_ = 0; r_ < 2; ++r_)                                           \
        _Pragma("unroll")                                                    \
        for (int c_ = 0; c_ < 2; ++c_)                                       \
            _Pragma("unroll")                                                 \
            for (int k_ = 0; k_ < 4; ++k_)                                   \
                acc[r_][c_] = __builtin_amdgcn_mfma_f32_16x16x32_fp8_fp8(    \
                    ah[r_][k_], bh[c_][k_], acc[r_][c_], 0, 0, 0);           \
    __builtin_amdgcn_s_setprio(0);

#define TILE(CUR, SSTAGE, WEND)                                              \
    {                                                                        \
        const u8* Bb = (CUR);                                                \
        SSTAGE;                                                              \
        RD_ALL(Bb);                                                          \
        MFMA16;                                                              \
        LG0; WEND; BARRIER;                                                  \
    }

// Shared core body: computes acc = A_tile(rowBase) x BT_tile(colBase)^T over
// K=2048 (operands fp8).  Declares acc/ah/bh and the epilogue geometry vars.
#define GEMM_CORE(Ap, BTp)                                                    \
    __shared__ __align__(16) u8 lds[32768];                                   \
    constexpr int PLBB = 8192;                                                \
    constexpr int BUFB = 16384;                                               \
    const int tid  = threadIdx.x;                                             \
    const int wave = tid >> 6, lane = tid & 63;                               \
    const int wr = wave >> 1, wc = wave & 1;                                  \
    const int l15 = lane & 15, qq = lane >> 4;                                \
    const int m = tid >> 3, sp = tid & 7;                                     \
    const u8* gA = (Ap)  + (size_t)(rowBase + m) * NM + (sp ^ (m & 7)) * 16;  \
    const u8* gB = (BTp) + (size_t)(colBase + m) * NM + (sp ^ (m & 7)) * 16;  \
    const int loffA = m * 128 + sp * 16;                                      \
    const int loffB = PLBB + m * 128 + sp * 16;                               \
    int offA[2][4], offB[2][4];                                               \
    _Pragma("unroll")                                                         \
    for (int r = 0; r < 2; ++r)                                               \
        _Pragma("unroll")                                                     \
        for (int kk = 0; kk < 4; ++kk) {                                      \
            const int row = wr * 32 + r * 16 + l15;                           \
            const int ch  = (2 * kk + (qq >> 1)) ^ (row & 7);                 \
            offA[r][kk] = row * 128 + ch * 16 + (qq & 1) * 8;                 \
        }                                                                     \
    _Pragma("unroll")                                                         \
    for (int c = 0; c < 2; ++c)                                               \
        _Pragma("unroll")                                                     \
        for (int kk = 0; kk < 4; ++kk) {                                      \
            const int row = wc * 32 + c * 16 + l15;                           \
            const int ch  = (2 * kk + (qq >> 1)) ^ (row & 7);                 \
            offB[c][kk] = PLBB + row * 128 + ch * 16 + (qq & 1) * 8;          \
        }                                                                     \
    float4v acc[2][2];                                                        \
    _Pragma("unroll")                                                         \
    for (int r = 0; r < 2; ++r)                                               \
        _Pragma("unroll")                                                     \
        for (int c = 0; c < 2; ++c)                                           \
            acc[r][c] = (float4v){0.f, 0.f, 0.f, 0.f};                        \
    long ah[2][4], bh[2][4];                                                  \
    u8* B0 = lds;                                                             \
    u8* B1 = lds + BUFB;                                                      \
    STAGE(B0);                                                                \
    W0; BARRIER;                                                              \
    _Pragma("unroll 1")                                                       \
    for (int i = 0; i < 7; ++i) {                                             \
        TILE(B0, STAGE(B1), W0)                                               \
        TILE(B1, STAGE(B0), W0)                                               \
    }                                                                         \
    TILE(B0, STAGE(B1), W0)                                                   \
    TILE(B1, NOST, NOST)

// ---------------------------------------------------------------------------
// GEMM1 (triangle): acc = 1024*(X*X^T) = -1024*X2 on tiles tcol <= trow.
// Epilogue writes (row,col) AND the mirror (col,row).
// ---------------------------------------------------------------------------
__global__ __launch_bounds__(256, 4) void gemm_sym_kernel(
    const u8* __restrict__ Xqp, const f16* __restrict__ Xf,
    f16* __restrict__ X2f, u8* __restrict__ X2q, u8* __restrict__ CTq)
{
    // Triangular index -> (trow, tcol), tcol <= trow, 528 tiles.
    const int bid = blockIdx.x;
    int trow = (int)((sqrtf(8.0f * (float)bid + 1.0f) - 1.0f) * 0.5f);
    while ((trow + 1) * (trow + 2) / 2 <= bid) ++trow;
    while (trow * (trow + 1) / 2 > bid) --trow;
    const int tcol = bid - trow * (trow + 1) / 2;
    const int rowBase = trow * 64, colBase = tcol * 64;

    GEMM_CORE(Xqp, Xqp)

    // Epilogue.  C/D layout: col = lane&15, row = qq*4 + g.
    #pragma unroll
    for (int r = 0; r < 2; ++r)
        #pragma unroll
        for (int c = 0; c < 2; ++c)
            #pragma unroll
            for (int g = 0; g < 4; ++g) {
                const int row = rowBase + wr * 32 + r * 16 + qq * 4 + g;
                const int col = colBase + wc * 32 + c * 16 + l15;
                const size_t off  = (size_t)row * NM + col;
                const size_t offT = (size_t)col * NM + row;
                const float x2 = -acc[r][c][g] * (1.0f / 1024.0f);
                const float x  = (float)Xf[off];
                const f16 x2h = (f16)x2;
                const u8  x2b = to_fp8(64.0f * x2);
                X2f[off]  = x2h;
                X2q[off]  = x2b;
                CTq[off]  = to_fp8(x2 * (256.0f / 24.0f) - x * (256.0f / 6.0f));
                // Mirror: X2 symmetric; X(col,row) = -x  =>  CT sign flips on x.
                X2f[offT] = x2h;
                X2q[offT] = x2b;
                CTq[offT] = to_fp8(x2 * (256.0f / 24.0f) + x * (256.0f / 6.0f));
            }
}

// ---------------------------------------------------------------------------
// GEMM2 (full): acc = 16384*(X2*C).  OUT = I + X + X2/2 + acc/16384.
// (r12 kernel unchanged)
// ---------------------------------------------------------------------------
__global__ __launch_bounds__(256, 4) void gemm_out_kernel(
    const u8* __restrict__ X2qp, const u8* __restrict__ CTqp,
    const f16* __restrict__ Xf, const f16* __restrict__ X2f,
    float* __restrict__ OUT)
{
    // XCD mapping: 32x32 tiles; each XCD gets an 8x16 rectangle.
    const int bid = blockIdx.x;
    const int xcd = bid & 7, li = bid >> 3;
    const int trow = (xcd & 3) * 8 + (li >> 4);
    const int tcol = (xcd >> 2) * 16 + (li & 15);
    const int rowBase = trow * 64, colBase = tcol * 64;

    GEMM_CORE(X2qp, CTqp)

    #pragma unroll
    for (int r = 0; r < 2; ++r)
        #pragma unroll
        for (int c = 0; c < 2; ++c)
            #pragma unroll
            for (int g = 0; g < 4; ++g) {
                const int row = rowBase + wr * 32 + r * 16 + qq * 4 + g;
                const int col = colBase + wc * 32 + c * 16 + l15;
                const size_t off = (size_t)row * NM + col;
                const float x  = (float)Xf[off];
                const float x2 = (float)X2f[off];
                float o = x + 0.5f * x2 + acc[r][c][g] * (1.0f / 16384.0f);
                if (row == col) o += 1.0f;
                OUT[off] = o;
            }
}

// ---------------------------------------------------------------------------
// exp(S) ~= T4(S) = I + X + X2/2 + X2*(X/6 + X2/24),  X = A - A^T.
// ws: X,X2 f16 (16.8MB) + Xq,X2q,CTq fp8 (12.6MB).  3 dispatches.
// ---------------------------------------------------------------------------
extern "C" void kernel_launch(void* const* d_in, const int* in_sizes, int n_in,
                              void* d_out, int out_size, void* d_ws, size_t ws_size,
                              hipStream_t stream) {
    const float* A = (const float*)d_in[0];
    float* out = (float*)d_out;
    const size_t NN = (size_t)NM * NM;

    f16* X   = (f16*)d_ws;
    f16* X2  = X + NN;
    u8*  Xq  = (u8*)(X2 + NN);
    u8*  X2q = Xq + NN;
    u8*  CTq = X2q + NN;

    dim3 tb(32, 8), tg(NM / 32, NM / 32);
    // 1) X = A - A^T (f16 + fp8(32X))
    skew_f16_kernel<<<tg, tb, 0, stream>>>(A, X, Xq);
    // 2) Lower triangle of X2 = X*X (via -X*X^T), mirrored; X2q, CTq planes
    gemm_sym_kernel<<<528, 256, 0, stream>>>(Xq, X, X2, X2q, CTq);
    // 3) OUT = I + X + X2/2 + (X2*C)
    gemm_out_kernel<<<1024, 256, 0, stream>>>(X2q, CTq, X, X2, out);
}

// Round 14
// 110.441 us; speedup vs baseline: 1.1191x; 1.1191x over previous
//
#include <hip/hip_runtime.h>
#include <stdint.h>
#include <math.h>

#define NM 2048

typedef _Float16 f16;
typedef unsigned char u8;
typedef __attribute__((ext_vector_type(4))) float float4v;
typedef __attribute__((ext_vector_type(4))) _Float16 half4;
typedef __attribute__((ext_vector_type(4))) unsigned int uint4v;

// float -> OCP e4m3 byte (RNE, hardware convert; gfx950 = OCP format)
__device__ inline u8 to_fp8(float v) {
    return (u8)(__builtin_amdgcn_cvt_pk_fp8_f32(v, v, 0, false) & 0xff);
}

// ---------------------------------------------------------------------------
// X = A - A^T: f16 master plane + fp8 operand plane Xq = fp8(32*X).
// ---------------------------------------------------------------------------
__global__ void skew_f16_kernel(const float* __restrict__ A, f16* __restrict__ X,
                                u8* __restrict__ Xq) {
    __shared__ float t[32][33];
    const int bx = blockIdx.x * 32, by = blockIdx.y * 32;
    const int tx = threadIdx.x, ty = threadIdx.y;
    #pragma unroll
    for (int r = 0; r < 32; r += 8)
        t[ty + r][tx] = A[(size_t)(bx + ty + r) * NM + by + tx];
    __syncthreads();
    #pragma unroll
    for (int r = 0; r < 32; r += 8) {
        const int i = by + ty + r, j = bx + tx;
        const float x = A[(size_t)i * NM + j] - t[tx][ty + r];
        X[(size_t)i * NM + j]  = (f16)x;
        Xq[(size_t)i * NM + j] = to_fp8(32.0f * x);
    }
}

// ---------------------------------------------------------------------------
// Round-14: triangle GEMM1 (r13's -48% FLOPs) + COALESCED mirror writes.
// r13 regressed (+13.7us) because mirrors were per-element stride-2048
// stores (~8-16x write amplification ~ 25-35us).  Fix: after the K-loop the
// 32KB LDS is free; stage the three mirror planes as TRANSPOSED 64x64 tiles
// in LDS (f16 8KB + 2 x u8 4KB, j-run XOR (i&7)<<2 keeps ds aliasing
// <=2-way), then stream mirror rows out with coalesced 8-16B stores.
// Diagonal tiles: direct and mirror values bitwise-identical -> benign.
// Core (r12-proven): 64x64 tiles, 4 waves, BK=128 fp8, 16 K-tiles, 1-phase
// loop {stage T+1 -> other buf; read T; 16 MFMA; LG0; W0; BARRIER}; static
// 32KB LDS; launch_bounds(256,4).  GEMM2 = r12/r13 kernel unchanged.
// ---------------------------------------------------------------------------
#define BARRIER asm volatile("s_barrier" ::: "memory")
#define LG0     asm volatile("s_waitcnt lgkmcnt(0)" ::: "memory")
#define W0      asm volatile("s_waitcnt vmcnt(0)" ::: "memory")
#define NOST    ((void)0)

#define GLL(src, dstoff)                                                      \
    __builtin_amdgcn_global_load_lds(                                         \
        (const __attribute__((address_space(1))) void*)(src),                 \
        (__attribute__((address_space(3))) void*)(uintptr_t)(dstoff),         \
        16, 0, 0)

#define STAGE(dst)                                                            \
    do {                                                                      \
        GLL(gA,                (dst) + loffA);                                \
        GLL(gA + 32 * NM,      (dst) + loffA + 4096);                         \
        GLL(gB,                (dst) + loffB);                                \
        GLL(gB + 32 * NM,      (dst) + loffB + 4096);                         \
        gA += 128; gB += 128;                                                 \
    } while (0)

#define RD_ALL(BB)                                                           \
    { _Pragma("unroll")                                                      \
      for (int r_ = 0; r_ < 2; ++r_)                                         \
        _Pragma("unroll")                                                    \
        for (int k_ = 0; k_ < 4; ++k_)                                       \
            ah[r_][k_] = *(const long*)((BB) + offA[r_][k_]);                \
      _Pragma("unroll")                                                      \
      for (int c_ = 0; c_ < 2; ++c_)                                         \
        _Pragma("unroll")                                                    \
        for (int k_ = 0; k_ < 4; ++k_)                                       \
            bh[c_][k_] = *(const long*)((BB) + offB[c_][k_]); }

#define MFMA16                                                               \
    __builtin_amdgcn_s_setprio(1);                                           \
    _Pragma("unroll")                                                        \
    for (int r_ = 0; r_ < 2; ++r_)                                           \
        _Pragma("unroll")                                                    \
        for (int c_ = 0; c_ < 2; ++c_)                                       \
            _Pragma("unroll")                                                 \
            for (int k_ = 0; k_ < 4; ++k_)                                   \
                acc[r_][c_] = __builtin_amdgcn_mfma_f32_16x16x32_fp8_fp8(    \
                    ah[r_][k_], bh[c_][k_], acc[r_][c_], 0, 0, 0);           \
    __builtin_amdgcn_s_setprio(0);

#define TILE(CUR, SSTAGE, WEND)                                              \
    {                                                                        \
        const u8* Bb = (CUR);                                                \
        SSTAGE;                                                              \
        RD_ALL(Bb);                                                          \
        MFMA16;                                                              \
        LG0; WEND; BARRIER;                                                  \
    }

// Shared core body: acc = A_tile(rowBase) x BT_tile(colBase)^T over K=2048.
#define GEMM_CORE(Ap, BTp)                                                    \
    __shared__ __align__(16) u8 lds[32768];                                   \
    constexpr int PLBB = 8192;                                                \
    constexpr int BUFB = 16384;                                               \
    const int tid  = threadIdx.x;                                             \
    const int wave = tid >> 6, lane = tid & 63;                               \
    const int wr = wave >> 1, wc = wave & 1;                                  \
    const int l15 = lane & 15, qq = lane >> 4;                                \
    const int m = tid >> 3, sp = tid & 7;                                     \
    const u8* gA = (Ap)  + (size_t)(rowBase + m) * NM + (sp ^ (m & 7)) * 16;  \
    const u8* gB = (BTp) + (size_t)(colBase + m) * NM + (sp ^ (m & 7)) * 16;  \
    const int loffA = m * 128 + sp * 16;                                      \
    const int loffB = PLBB + m * 128 + sp * 16;                               \
    int offA[2][4], offB[2][4];                                               \
    _Pragma("unroll")                                                         \
    for (int r = 0; r < 2; ++r)                                               \
        _Pragma("unroll")                                                     \
        for (int kk = 0; kk < 4; ++kk) {                                      \
            const int row = wr * 32 + r * 16 + l15;                           \
            const int ch  = (2 * kk + (qq >> 1)) ^ (row & 7);                 \
            offA[r][kk] = row * 128 + ch * 16 + (qq & 1) * 8;                 \
        }                                                                     \
    _Pragma("unroll")                                                         \
    for (int c = 0; c < 2; ++c)                                               \
        _Pragma("unroll")                                                     \
        for (int kk = 0; kk < 4; ++kk) {                                      \
            const int row = wc * 32 + c * 16 + l15;                           \
            const int ch  = (2 * kk + (qq >> 1)) ^ (row & 7);                 \
            offB[c][kk] = PLBB + row * 128 + ch * 16 + (qq & 1) * 8;          \
        }                                                                     \
    float4v acc[2][2];                                                        \
    _Pragma("unroll")                                                         \
    for (int r = 0; r < 2; ++r)                                               \
        _Pragma("unroll")                                                     \
        for (int c = 0; c < 2; ++c)                                           \
            acc[r][c] = (float4v){0.f, 0.f, 0.f, 0.f};                        \
    long ah[2][4], bh[2][4];                                                  \
    u8* B0 = lds;                                                             \
    u8* B1 = lds + BUFB;                                                      \
    STAGE(B0);                                                                \
    W0; BARRIER;                                                              \
    _Pragma("unroll 1")                                                       \
    for (int i = 0; i < 7; ++i) {                                             \
        TILE(B0, STAGE(B1), W0)                                               \
        TILE(B1, STAGE(B0), W0)                                               \
    }                                                                         \
    TILE(B0, STAGE(B1), W0)                                                   \
    TILE(B1, NOST, NOST)

// ---------------------------------------------------------------------------
// GEMM1 (triangle): acc = 1024*(X*X^T) = -1024*X2 on tiles tcol <= trow.
// Direct writes coalesced; mirrors staged transposed in LDS, then coalesced.
// ---------------------------------------------------------------------------
__global__ __launch_bounds__(256, 4) void gemm_sym_kernel(
    const u8* __restrict__ Xqp, const f16* __restrict__ Xf,
    f16* __restrict__ X2f, u8* __restrict__ X2q, u8* __restrict__ CTq)
{
    // Triangular index -> (trow, tcol), tcol <= trow, 528 tiles.
    const int bid = blockIdx.x;
    int trow = (int)((sqrtf(8.0f * (float)bid + 1.0f) - 1.0f) * 0.5f);
    while ((trow + 1) * (trow + 2) / 2 <= bid) ++trow;
    while (trow * (trow + 1) / 2 > bid) --trow;
    const int tcol = bid - trow * (trow + 1) / 2;
    const int rowBase = trow * 64, colBase = tcol * 64;

    GEMM_CORE(Xqp, Xqp)

    // ---- direct writes (coalesced) + stage mirrors transposed in LDS ----
    // LDS free after the K-loop's final LG0+BARRIER.  Transposed tile
    // [i=col_local][j=row_local], j-run XOR'd by (i&7)<<2 (2-way banks).
    f16* Tx2 = (f16*)lds;        // 8 KB
    u8*  Tq  = lds + 8192;       // 4 KB
    u8*  Tc  = lds + 12288;      // 4 KB
    #pragma unroll
    for (int r = 0; r < 2; ++r)
        #pragma unroll
        for (int c = 0; c < 2; ++c) {
            const int i  = wc * 32 + c * 16 + l15;     // col_local
            const int j0 = wr * 32 + r * 16 + qq * 4;  // row_local base
            const int jx = j0 ^ ((i & 7) << 2);
            half4 hx;
            unsigned qw = 0, cw = 0;
            #pragma unroll
            for (int g = 0; g < 4; ++g) {
                const int row = rowBase + j0 + g;
                const int col = colBase + i;
                const size_t off = (size_t)row * NM + col;
                const float x2 = -acc[r][c][g] * (1.0f / 1024.0f);
                const float x  = (float)Xf[off];
                const f16 x2h = (f16)x2;
                const u8  x2b = to_fp8(64.0f * x2);
                X2f[off] = x2h;
                X2q[off] = x2b;
                CTq[off] = to_fp8(x2 * (256.0f / 24.0f) - x * (256.0f / 6.0f));
                hx[g] = x2h;
                qw |= (unsigned)x2b << (8 * g);
                // Mirror: X(col,row) = -x  =>  CT sign flips on the x term.
                cw |= (unsigned)to_fp8(x2 * (256.0f / 24.0f) + x * (256.0f / 6.0f)) << (8 * g);
            }
            *(half4*)&Tx2[i * 64 + jx]   = hx;
            *(unsigned*)&Tq[i * 64 + jx] = qw;
            *(unsigned*)&Tc[i * 64 + jx] = cw;
        }
    LG0; BARRIER;

    // ---- coalesced mirror writes: thread tid -> mirror row colBase+ti ----
    {
        const int ti = tid >> 2, q4 = tid & 3;
        const int swz = (ti & 7) << 2;
        const size_t mbase = (size_t)(colBase + ti) * NM + rowBase + q4 * 16;
        #pragma unroll
        for (int jj = 0; jj < 4; ++jj) {
            const int jl = q4 * 16 + jj * 4;
            const half4 hv = *(const half4*)&Tx2[ti * 64 + (jl ^ swz)];
            *(half4*)&X2f[mbase + jj * 4] = hv;
        }
        unsigned mq[4], mc[4];
        #pragma unroll
        for (int jj = 0; jj < 4; ++jj) {
            const int jl = q4 * 16 + jj * 4;
            mq[jj] = *(const unsigned*)&Tq[ti * 64 + (jl ^ swz)];
            mc[jj] = *(const unsigned*)&Tc[ti * 64 + (jl ^ swz)];
        }
        *(uint4v*)&X2q[mbase] = (uint4v){mq[0], mq[1], mq[2], mq[3]};
        *(uint4v*)&CTq[mbase] = (uint4v){mc[0], mc[1], mc[2], mc[3]};
    }
}

// ---------------------------------------------------------------------------
// GEMM2 (full): acc = 16384*(X2*C).  OUT = I + X + X2/2 + acc/16384.
// (r12 kernel unchanged)
// ---------------------------------------------------------------------------
__global__ __launch_bounds__(256, 4) void gemm_out_kernel(
    const u8* __restrict__ X2qp, const u8* __restrict__ CTqp,
    const f16* __restrict__ Xf, const f16* __restrict__ X2f,
    float* __restrict__ OUT)
{
    // XCD mapping: 32x32 tiles; each XCD gets an 8x16 rectangle.
    const int bid = blockIdx.x;
    const int xcd = bid & 7, li = bid >> 3;
    const int trow = (xcd & 3) * 8 + (li >> 4);
    const int tcol = (xcd >> 2) * 16 + (li & 15);
    const int rowBase = trow * 64, colBase = tcol * 64;

    GEMM_CORE(X2qp, CTqp)

    #pragma unroll
    for (int r = 0; r < 2; ++r)
        #pragma unroll
        for (int c = 0; c < 2; ++c)
            #pragma unroll
            for (int g = 0; g < 4; ++g) {
                const int row = rowBase + wr * 32 + r * 16 + qq * 4 + g;
                const int col = colBase + wc * 32 + c * 16 + l15;
                const size_t off = (size_t)row * NM + col;
                const float x  = (float)Xf[off];
                const float x2 = (float)X2f[off];
                float o = x + 0.5f * x2 + acc[r][c][g] * (1.0f / 16384.0f);
                if (row == col) o += 1.0f;
                OUT[off] = o;
            }
}

// ---------------------------------------------------------------------------
// exp(S) ~= T4(S) = I + X + X2/2 + X2*(X/6 + X2/24),  X = A - A^T.
// ws: X,X2 f16 (16.8MB) + Xq,X2q,CTq fp8 (12.6MB).  3 dispatches.
// ---------------------------------------------------------------------------
extern "C" void kernel_launch(void* const* d_in, const int* in_sizes, int n_in,
                              void* d_out, int out_size, void* d_ws, size_t ws_size,
                              hipStream_t stream) {
    const float* A = (const float*)d_in[0];
    float* out = (float*)d_out;
    const size_t NN = (size_t)NM * NM;

    f16* X   = (f16*)d_ws;
    f16* X2  = X + NN;
    u8*  Xq  = (u8*)(X2 + NN);
    u8*  X2q = Xq + NN;
    u8*  CTq = X2q + NN;

    dim3 tb(32, 8), tg(NM / 32, NM / 32);
    // 1) X = A - A^T (f16 + fp8(32X))
    skew_f16_kernel<<<tg, tb, 0, stream>>>(A, X, Xq);
    // 2) Lower triangle of X2 = X*X (via -X*X^T), mirrored via LDS transpose
    gemm_sym_kernel<<<528, 256, 0, stream>>>(Xq, X, X2, X2q, CTq);
    // 3) OUT = I + X + X2/2 + (X2*C)
    gemm_out_kernel<<<1024, 256, 0, stream>>>(X2q, CTq, X, X2, out);
}

// Round 15
// 105.470 us; speedup vs baseline: 1.1719x; 1.0471x over previous
//
#include <hip/hip_runtime.h>
#include <stdint.h>
#include <math.h>

#define NM 2048

typedef _Float16 f16;
typedef unsigned char u8;
typedef __attribute__((ext_vector_type(4))) float float4v;
typedef __attribute__((ext_vector_type(4))) _Float16 half4;
typedef __attribute__((ext_vector_type(4))) unsigned int uint4v;

// float -> OCP e4m3 byte (RNE, hardware convert; gfx950 = OCP format)
__device__ inline u8 to_fp8(float v) {
    return (u8)(__builtin_amdgcn_cvt_pk_fp8_f32(v, v, 0, false) & 0xff);
}

// ---------------------------------------------------------------------------
// Round-15 skew: PAIR-TILE.  X = A - A^T with each block handling the
// symmetric 32x32 tile pair (P,Q) and (Q,P), P<=Q: each A tile is read ONCE
// (registers + transposed LDS copy), both X tiles written.  A traffic
// halves: 44 MB -> 28 MB.  Diagonal blocks double-write identical values
// (same formula both passes) - benign.  Grid = 2080 pairs.
// x(P,Q)[i][j] = D1[i][j] - t2[j][i];  x(Q,P)[a][b] = D2[a][b] - t1[b][a].
// ---------------------------------------------------------------------------
__global__ void skew_pair_kernel(const float* __restrict__ A, f16* __restrict__ X,
                                 u8* __restrict__ Xq) {
    __shared__ float t1[32][33], t2[32][33];
    // Pair index -> (P, Q), P <= Q over 64x64 tiles: 2080 pairs.
    const int bid = blockIdx.x;
    int P = (int)((sqrtf(8.0f * (float)bid + 1.0f) - 1.0f) * 0.5f);
    while ((P + 1) * (P + 2) / 2 <= bid) ++P;
    while (P * (P + 1) / 2 > bid) --P;
    const int Q = 63 - (bid - P * (P + 1) / 2);   // map to Q >= ... any bijection
    const int Pr = P, Qr = (Q >= P) ? Q : 63 - Q; // guard (see note below)
    // NOTE: simple exact mapping instead: Q2 = P + (bid - P*(P+1)/2) is wrong
    // for upper triangle; use direct lower-triangle pairs (Qr>=Pr) via:
    const int tri = bid - P * (P + 1) / 2;        // 0..P
    const int PP = tri;                           // col-block (<= P)
    const int QQ = P;                             // row-block
    (void)Pr; (void)Qr; (void)Q;
    const int pBase = PP * 32, qBase = QQ * 32;   // PP <= QQ

    const int tx = threadIdx.x, ty = threadIdx.y;
    float d1[4], d2[4];
    // D1 = A[pBase.., qBase..] ; D2 = A[qBase.., pBase..]
    #pragma unroll
    for (int r = 0; r < 4; ++r) {
        d1[r] = A[(size_t)(pBase + ty + r * 8) * NM + qBase + tx];
        d2[r] = A[(size_t)(qBase + ty + r * 8) * NM + pBase + tx];
        t1[ty + r * 8][tx] = d1[r];
        t2[ty + r * 8][tx] = d2[r];
    }
    __syncthreads();
    #pragma unroll
    for (int r = 0; r < 4; ++r) {
        // X(PP,QQ)[i][j] = D1[i][j] - D2[j][i]
        {
            const int i = pBase + ty + r * 8, j = qBase + tx;
            const float x = d1[r] - t2[tx][ty + r * 8];
            X[(size_t)i * NM + j]  = (f16)x;
            Xq[(size_t)i * NM + j] = to_fp8(32.0f * x);
        }
        // X(QQ,PP)[a][b] = D2[a][b] - D1[b][a]
        {
            const int a = qBase + ty + r * 8, b = pBase + tx;
            const float x = d2[r] - t1[tx][ty + r * 8];
            X[(size_t)a * NM + b]  = (f16)x;
            Xq[(size_t)a * NM + b] = to_fp8(32.0f * x);
        }
    }
}

// ---------------------------------------------------------------------------
// GEMM core (r12-proven): 64x64 tiles, 4 waves (wave tile 32x32), BK=128
// fp8, 16 K-tiles, 1-phase loop {stage T+1 -> other buf; read T; 16 MFMA;
// LG0; W0; BARRIER}; static 32KB LDS; launch_bounds(256,4).
// ---------------------------------------------------------------------------
#define BARRIER asm volatile("s_barrier" ::: "memory")
#define LG0     asm volatile("s_waitcnt lgkmcnt(0)" ::: "memory")
#define W0      asm volatile("s_waitcnt vmcnt(0)" ::: "memory")
#define NOST    ((void)0)

#define GLL(src, dstoff)                                                      \
    __builtin_amdgcn_global_load_lds(                                         \
        (const __attribute__((address_space(1))) void*)(src),                 \
        (__attribute__((address_space(3))) void*)(uintptr_t)(dstoff),         \
        16, 0, 0)

#define STAGE(dst)                                                            \
    do {                                                                      \
        GLL(gA,                (dst) + loffA);                                \
        GLL(gA + 32 * NM,      (dst) + loffA + 4096);                         \
        GLL(gB,                (dst) + loffB);                                \
        GLL(gB + 32 * NM,      (dst) + loffB + 4096);                         \
        gA += 128; gB += 128;                                                 \
    } while (0)

#define RD_ALL(BB)                                                           \
    { _Pragma("unroll")                                                      \
      for (int r_ = 0; r_ < 2; ++r_)                                         \
        _Pragma("unroll")                                                    \
        for (int k_ = 0; k_ < 4; ++k_)                                       \
            ah[r_][k_] = *(const long*)((BB) + offA[r_][k_]);                \
      _Pragma("unroll")                                                      \
      for (int c_ = 0; c_ < 2; ++c_)                                         \
        _Pragma("unroll")                                                    \
        for (int k_ = 0; k_ < 4; ++k_)                                       \
            bh[c_][k_] = *(const long*)((BB) + offB[c_][k_]); }

#define MFMA16                                                               \
    __builtin_amdgcn_s_setprio(1);                                           \
    _Pragma("unroll")                                                        \
    for (int r_ = 0; r_ < 2; ++r_)                                           \
        _Pragma("unroll")                                                    \
        for (int c_ = 0; c_ < 2; ++c_)                                       \
            _Pragma("unroll")                                                 \
            for (int k_ = 0; k_ < 4; ++k_)                                   \
                acc[r_][c_] = __builtin_amdgcn_mfma_f32_16x16x32_fp8_fp8(    \
                    ah[r_][k_], bh[c_][k_], acc[r_][c_], 0, 0, 0);           \
    __builtin_amdgcn_s_setprio(0);

#define TILE(CUR, SSTAGE, WEND)                                              \
    {                                                                        \
        const u8* Bb = (CUR);                                                \
        SSTAGE;                                                              \
        RD_ALL(Bb);                                                          \
        MFMA16;                                                              \
        LG0; WEND; BARRIER;                                                  \
    }

#define GEMM_CORE(Ap, BTp)                                                    \
    __shared__ __align__(16) u8 lds[32768];                                   \
    constexpr int PLBB = 8192;                                                \
    constexpr int BUFB = 16384;                                               \
    const int tid  = threadIdx.x;                                             \
    const int wave = tid >> 6, lane = tid & 63;                               \
    const int wr = wave >> 1, wc = wave & 1;                                  \
    const int l15 = lane & 15, qq = lane >> 4;                                \
    const int m = tid >> 3, sp = tid & 7;                                     \
    const u8* gA = (Ap)  + (size_t)(rowBase + m) * NM + (sp ^ (m & 7)) * 16;  \
    const u8* gB = (BTp) + (size_t)(colBase + m) * NM + (sp ^ (m & 7)) * 16;  \
    const int loffA = m * 128 + sp * 16;                                      \
    const int loffB = PLBB + m * 128 + sp * 16;                               \
    int offA[2][4], offB[2][4];                                               \
    _Pragma("unroll")                                                         \
    for (int r = 0; r < 2; ++r)                                               \
        _Pragma("unroll")                                                     \
        for (int kk = 0; kk < 4; ++kk) {                                      \
            const int row = wr * 32 + r * 16 + l15;                           \
            const int ch  = (2 * kk + (qq >> 1)) ^ (row & 7);                 \
            offA[r][kk] = row * 128 + ch * 16 + (qq & 1) * 8;                 \
        }                                                                     \
    _Pragma("unroll")                                                         \
    for (int c = 0; c < 2; ++c)                                               \
        _Pragma("unroll")                                                     \
        for (int kk = 0; kk < 4; ++kk) {                                      \
            const int row = wc * 32 + c * 16 + l15;                           \
            const int ch  = (2 * kk + (qq >> 1)) ^ (row & 7);                 \
            offB[c][kk] = PLBB + row * 128 + ch * 16 + (qq & 1) * 8;          \
        }                                                                     \
    float4v acc[2][2];                                                        \
    _Pragma("unroll")                                                         \
    for (int r = 0; r < 2; ++r)                                               \
        _Pragma("unroll")                                                     \
        for (int c = 0; c < 2; ++c)                                           \
            acc[r][c] = (float4v){0.f, 0.f, 0.f, 0.f};                        \
    long ah[2][4], bh[2][4];                                                  \
    u8* B0 = lds;                                                             \
    u8* B1 = lds + BUFB;                                                      \
    STAGE(B0);                                                                \
    W0; BARRIER;                                                              \
    _Pragma("unroll 1")                                                       \
    for (int i = 0; i < 7; ++i) {                                             \
        TILE(B0, STAGE(B1), W0)                                               \
        TILE(B1, STAGE(B0), W0)                                               \
    }                                                                         \
    TILE(B0, STAGE(B1), W0)                                                   \
    TILE(B1, NOST, NOST)

// ---------------------------------------------------------------------------
// GEMM1 (triangle, XCD-swizzled): acc = -1024*X2 on tiles tcol <= trow.
// Direct writes coalesced; mirrors staged transposed in LDS (r14-proven).
// 528 = 8 x 66 -> bijective chunked XCD swizzle clusters each XCD's tiles.
// ---------------------------------------------------------------------------
__global__ __launch_bounds__(256, 4) void gemm_sym_kernel(
    const u8* __restrict__ Xqp, const f16* __restrict__ Xf,
    f16* __restrict__ X2f, u8* __restrict__ X2q, u8* __restrict__ CTq)
{
    // XCD chunked swizzle (bijective: 528 = 8*66), then triangle decode.
    const int bid = (blockIdx.x & 7) * 66 + (blockIdx.x >> 3);
    int trow = (int)((sqrtf(8.0f * (float)bid + 1.0f) - 1.0f) * 0.5f);
    while ((trow + 1) * (trow + 2) / 2 <= bid) ++trow;
    while (trow * (trow + 1) / 2 > bid) --trow;
    const int tcol = bid - trow * (trow + 1) / 2;
    const int rowBase = trow * 64, colBase = tcol * 64;

    GEMM_CORE(Xqp, Xqp)

    // Direct writes + transposed mirror staging in LDS (free after K-loop).
    f16* Tx2 = (f16*)lds;        // 8 KB
    u8*  Tq  = lds + 8192;       // 4 KB
    u8*  Tc  = lds + 12288;      // 4 KB
    #pragma unroll
    for (int r = 0; r < 2; ++r)
        #pragma unroll
        for (int c = 0; c < 2; ++c) {
            const int i  = wc * 32 + c * 16 + l15;     // col_local
            const int j0 = wr * 32 + r * 16 + qq * 4;  // row_local base
            const int jx = j0 ^ ((i & 7) << 2);
            half4 hx;
            unsigned qw = 0, cw = 0;
            #pragma unroll
            for (int g = 0; g < 4; ++g) {
                const int row = rowBase + j0 + g;
                const int col = colBase + i;
                const size_t off = (size_t)row * NM + col;
                const float x2 = -acc[r][c][g] * (1.0f / 1024.0f);
                const float x  = (float)Xf[off];
                const f16 x2h = (f16)x2;
                const u8  x2b = to_fp8(64.0f * x2);
                X2f[off] = x2h;
                X2q[off] = x2b;
                CTq[off] = to_fp8(x2 * (256.0f / 24.0f) - x * (256.0f / 6.0f));
                hx[g] = x2h;
                qw |= (unsigned)x2b << (8 * g);
                cw |= (unsigned)to_fp8(x2 * (256.0f / 24.0f) + x * (256.0f / 6.0f)) << (8 * g);
            }
            *(half4*)&Tx2[i * 64 + jx]   = hx;
            *(unsigned*)&Tq[i * 64 + jx] = qw;
            *(unsigned*)&Tc[i * 64 + jx] = cw;
        }
    LG0; BARRIER;

    // Coalesced mirror writes: thread tid -> mirror row colBase+ti.
    {
        const int ti = tid >> 2, q4 = tid & 3;
        const int swz = (ti & 7) << 2;
        const size_t mbase = (size_t)(colBase + ti) * NM + rowBase + q4 * 16;
        #pragma unroll
        for (int jj = 0; jj < 4; ++jj) {
            const int jl = q4 * 16 + jj * 4;
            const half4 hv = *(const half4*)&Tx2[ti * 64 + (jl ^ swz)];
            *(half4*)&X2f[mbase + jj * 4] = hv;
        }
        unsigned mq[4], mc[4];
        #pragma unroll
        for (int jj = 0; jj < 4; ++jj) {
            const int jl = q4 * 16 + jj * 4;
            mq[jj] = *(const unsigned*)&Tq[ti * 64 + (jl ^ swz)];
            mc[jj] = *(const unsigned*)&Tc[ti * 64 + (jl ^ swz)];
        }
        *(uint4v*)&X2q[mbase] = (uint4v){mq[0], mq[1], mq[2], mq[3]};
        *(uint4v*)&CTq[mbase] = (uint4v){mc[0], mc[1], mc[2], mc[3]};
    }
}

// ---------------------------------------------------------------------------
// GEMM2 (full): acc = 16384*(X2*C).  OUT = I + X + X2/2 + acc/16384.
// ---------------------------------------------------------------------------
__global__ __launch_bounds__(256, 4) void gemm_out_kernel(
    const u8* __restrict__ X2qp, const u8* __restrict__ CTqp,
    const f16* __restrict__ Xf, const f16* __restrict__ X2f,
    float* __restrict__ OUT)
{
    const int bid = blockIdx.x;
    const int xcd = bid & 7, li = bid >> 3;
    const int trow = (xcd & 3) * 8 + (li >> 4);
    const int tcol = (xcd >> 2) * 16 + (li & 15);
    const int rowBase = trow * 64, colBase = tcol * 64;

    GEMM_CORE(X2qp, CTqp)

    #pragma unroll
    for (int r = 0; r < 2; ++r)
        #pragma unroll
        for (int c = 0; c < 2; ++c)
            #pragma unroll
            for (int g = 0; g < 4; ++g) {
                const int row = rowBase + wr * 32 + r * 16 + qq * 4 + g;
                const int col = colBase + wc * 32 + c * 16 + l15;
                const size_t off = (size_t)row * NM + col;
                const float x  = (float)Xf[off];
                const float x2 = (float)X2f[off];
                float o = x + 0.5f * x2 + acc[r][c][g] * (1.0f / 16384.0f);
                if (row == col) o += 1.0f;
                OUT[off] = o;
            }
}

// ---------------------------------------------------------------------------
// exp(S) ~= T4(S) = I + X + X2/2 + X2*(X/6 + X2/24),  X = A - A^T.
// ws: X,X2 f16 (16.8MB) + Xq,X2q,CTq fp8 (12.6MB).  3 dispatches.
// ---------------------------------------------------------------------------
extern "C" void kernel_launch(void* const* d_in, const int* in_sizes, int n_in,
                              void* d_out, int out_size, void* d_ws, size_t ws_size,
                              hipStream_t stream) {
    const float* A = (const float*)d_in[0];
    float* out = (float*)d_out;
    const size_t NN = (size_t)NM * NM;

    f16* X   = (f16*)d_ws;
    f16* X2  = X + NN;
    u8*  Xq  = (u8*)(X2 + NN);
    u8*  X2q = Xq + NN;
    u8*  CTq = X2q + NN;

    dim3 tb(32, 8);
    // 1) X = A - A^T, pair-tiled (A read once); f16 + fp8(32X)
    skew_pair_kernel<<<2080, tb, 0, stream>>>(A, X, Xq);
    // 2) Lower triangle of X2 = X*X, mirrored via LDS transpose
    gemm_sym_kernel<<<528, 256, 0, stream>>>(Xq, X, X2, X2q, CTq);
    // 3) OUT = I + X + X2/2 + (X2*C)
    gemm_out_kernel<<<1024, 256, 0, stream>>>(X2q, CTq, X, X2, out);
}